// Round 8
// baseline (724.069 us; speedup 1.0000x reference)
//
#include <hip/hip_runtime.h>
#include <hip/hip_bf16.h>
#include <cstdint>

typedef unsigned int u32;
typedef unsigned long long u64;

#define ANUM 131072
#define BATCH 4
#define PRE 3000
#define CAP 4096
#define NW 47          /* ceil(3000/64) */
#define MROW 48        /* padded u64 words per mask row */
#define MAXOUT 1000
#define NBUCK 64       /* candidate buckets per batch */
#define BCAP 256       /* slots per bucket */

/* ---- workspace layout (bytes) ----
 * cand aliases hist1 (dead after k_sel1); diag aliases hist2 (dead after k_sel2)
 */
#define OFF_CAND  0ul                  /* u64[B][NBUCK][BCAP] = 512KB (aliases hist1) */
#define OFF_HIST1 0ul                  /* u32[B][65536] = 1MB */
#define OFF_HIST2 1048576ul            /* u32[B][65536] = 1MB */
#define OFF_DIAG  1048576ul            /* u64[B][NW][64] = 96256 (aliases hist2) */
#define OFF_INFO  2097152ul            /* u32[256] */
#define OFF_BCNT  2098176ul            /* u32[B*NBUCK*16] (64B-padded counters) */
#define OFF_ORDER 2114560ul            /* u32[B][PRE] */
#define OFF_SCORE 2162560ul            /* f32[B][PRE] */
#define OFF_BOXES 2210560ul            /* f32[B][PRE][6] */
#define OFF_MASKS 2498560ul            /* u64[B][PRE][MROW] = 4608000 */
#define OFF_KEPT  7106560ul            /* u32[B][PRE] -> end 7154560 */
#define MEMSET_BYTES 2114560ul         /* hists + info + bcnt */

__device__ __forceinline__ u32 score_key(float f) {
  u32 u = __float_as_uint(f);
  return (u & 0x80000000u) ? ~u : (u | 0x80000000u);
}

/* ---------- 1. histogram of top 16 bits ---------- */
__global__ void k_hist1(const float* __restrict__ scores, u32* __restrict__ hist) {
  int t = blockIdx.x * blockDim.x + threadIdx.x;
  int b = t >> 17;
  u32 key = score_key(scores[t]);
  atomicAdd(&hist[(b << 16) + (key >> 16)], 1u);
}

/* ---------- 2. find high-16 bin crossing rank 3000 ---------- */
__global__ void k_sel1(const u32* __restrict__ hist, u32* __restrict__ info) {
  int b = blockIdx.x, tid = threadIdx.x;              /* 256 threads */
  __shared__ u32 part[256];
  const u32* h = hist + (b << 16);
  u32 s = 0;
  for (int r = tid * 256; r < tid * 256 + 256; ++r) s += h[65535 - r];
  part[tid] = s;
  __syncthreads();
  if (tid == 0) {
    u32 c = 0; int tstar = 0; u32 cb = 0;
    for (int t = 0; t < 256; ++t) {
      if (c + part[t] >= PRE) { tstar = t; cb = c; break; }
      c += part[t];
    }
    u32 cc = cb; int b16 = 0;
    for (int r = tstar * 256; r < 65536; ++r) {
      u32 cnt = h[65535 - r];
      if (cc + cnt >= PRE) { b16 = 65535 - r; break; }
      cc += cnt;
    }
    info[b] = (u32)b16;
    info[4 + b] = cc;
  }
}

/* ---------- 3. histogram of low 16 bits within the boundary bin ---------- */
__global__ void k_hist2(const float* __restrict__ scores, const u32* __restrict__ info,
                        u32* __restrict__ hist2) {
  int t = blockIdx.x * blockDim.x + threadIdx.x;
  int b = t >> 17;
  u32 key = score_key(scores[t]);
  if ((key >> 16) == info[b])
    atomicAdd(&hist2[(b << 16) + (key & 0xFFFFu)], 1u);
}

/* ---------- 4. exact threshold key T ---------- */
__global__ void k_sel2(const u32* __restrict__ hist2, u32* __restrict__ info) {
  int b = blockIdx.x, tid = threadIdx.x;
  __shared__ u32 part[256];
  const u32* h = hist2 + (b << 16);
  u32 s = 0;
  for (int r = tid * 256; r < tid * 256 + 256; ++r) s += h[65535 - r];
  part[tid] = s;
  __syncthreads();
  if (tid == 0) {
    int target = PRE - (int)info[4 + b];
    u32 c = 0; int tstar = 0; u32 cb = 0;
    for (int t = 0; t < 256; ++t) {
      if ((int)(c + part[t]) >= target) { tstar = t; cb = c; break; }
      c += part[t];
    }
    u32 cc = cb; int t16 = 0;
    for (int r = tstar * 256; r < 65536; ++r) {
      u32 cnt = h[65535 - r];
      if ((int)(cc + cnt) >= target) { t16 = 65535 - r; break; }
      cc += cnt;
    }
    info[8 + b] = (info[b] << 16) | (u32)t16;
  }
}

/* ---------- 5. compact candidates (key >= T) into per-bucket lists ---------- */
__global__ void k_compact(const float* __restrict__ scores, const u32* __restrict__ info,
                          u32* __restrict__ bcnt, u64* __restrict__ cand) {
  int t = blockIdx.x * blockDim.x + threadIdx.x;
  int b = t >> 17;
  int e = t & (ANUM - 1);
  int bucket = (blockIdx.x >> 3) & (NBUCK - 1);
  u32 key = score_key(scores[t]);
  if (key >= info[8 + b]) {
    u32 pos = atomicAdd(&bcnt[(u32)((b << 6) + bucket) * 16u], 1u);
    if (pos < BCAP) cand[(size_t)((b << 6) + bucket) * BCAP + pos] = ((u64)key << 32) | (u32)(~(u32)e);
  }
}

/* ---------- 6. gather buckets + bitonic sort (descending) ---------- */
__global__ __launch_bounds__(1024) void k_sort(const u64* __restrict__ cand,
                                               const u32* __restrict__ bcnt,
                                               u32* __restrict__ order,
                                               float* __restrict__ scoresel) {
  int b = blockIdx.x, tid = threadIdx.x;
  __shared__ u64 s[CAP];
  __shared__ u32 pref[NBUCK + 1];
  if (tid < NBUCK) {
    u32 c = bcnt[(u32)((b << 6) + tid) * 16u];
    if (c > BCAP) c = BCAP;
    u32 inc = c;
#pragma unroll
    for (int d = 1; d < 64; d <<= 1) {
      u32 v = __shfl_up(inc, d);
      if (tid >= d) inc += v;
    }
    pref[tid + 1] = inc;
    if (tid == 0) pref[0] = 0;
  }
  __syncthreads();
  for (int i = tid; i < CAP; i += 1024) s[i] = 0ull;
  __syncthreads();
  for (int j = tid; j < NBUCK * BCAP; j += 1024) {
    int bk = j >> 8, sl = j & (BCAP - 1);
    u32 c = pref[bk + 1] - pref[bk];
    if ((u32)sl < c) s[pref[bk] + sl] = cand[(size_t)((b << 6) + bk) * BCAP + sl];
  }
  __syncthreads();
  for (int k = 2; k <= CAP; k <<= 1) {
    for (int j = k >> 1; j > 0; j >>= 1) {
      for (int i = tid; i < CAP; i += 1024) {
        int ixj = i ^ j;
        if (ixj > i) {
          u64 a = s[i], c = s[ixj];
          bool up = ((i & k) == 0);
          if (up ? (a < c) : (a > c)) { s[i] = c; s[ixj] = a; }
        }
      }
      __syncthreads();
    }
  }
  for (int i = tid; i < PRE; i += 1024) {
    u64 kv = s[i];
    u32 key = (u32)(kv >> 32);
    u32 e = ~((u32)kv);
    order[b * PRE + i] = e;
    u32 u = (key & 0x80000000u) ? (key ^ 0x80000000u) : ~key;
    scoresel[b * PRE + i] = __uint_as_float(u);
  }
}

/* ---------- 7. gather + box regression ---------- */
__global__ void k_regress(const float* __restrict__ anchors, const float* __restrict__ deltas,
                          const u32* __restrict__ order, float* __restrict__ boxes) {
  int t = blockIdx.x * blockDim.x + threadIdx.x;
  if (t >= BATCH * PRE) return;
  int b = t / PRE;
  u32 a = order[t];
  const float* an = anchors + (size_t)a * 6;
  const float* de = deltas + ((size_t)b * ANUM + a) * 6;
  float* out = boxes + (size_t)t * 6;
#pragma unroll
  for (int d = 0; d < 3; ++d) {
    float lo = an[d], hi = an[3 + d];
    float dims = __fsub_rn(hi, lo);
    float ctr = __fadd_rn(lo, __fmul_rn(0.5f, dims));
    ctr = __fadd_rn(ctr, __fmul_rn(de[d], dims));
    float nd = __fmul_rn(dims, expf(de[3 + d]));
    float h = __fmul_rn(0.5f, nd);
    out[d] = __fsub_rn(ctr, h);
    out[3 + d] = __fadd_rn(ctr, h);
  }
}

/* ---------- 8. suppression bitmask matrix (+ diag blocks) ---------- */
__global__ void k_mask(const float* __restrict__ boxes, u64* __restrict__ masks,
                       u64* __restrict__ diag) {
  int jblk = blockIdx.x, iblk = blockIdx.y, b = blockIdx.z;
  int tid = threadIdx.x;                                /* 64 */
  __shared__ float cb[64][7];
  int j0 = jblk * 64;
  {
    int jj = j0 + tid; if (jj > PRE - 1) jj = PRE - 1;
    const float* src = boxes + ((size_t)b * PRE + jj) * 6;
#pragma unroll
    for (int d = 0; d < 6; ++d) cb[tid][d] = src[d];
    float dx = fmaxf(__fsub_rn(cb[tid][3], cb[tid][0]), 0.0f);
    float dy = fmaxf(__fsub_rn(cb[tid][4], cb[tid][1]), 0.0f);
    float dz = fmaxf(__fsub_rn(cb[tid][5], cb[tid][2]), 0.0f);
    cb[tid][6] = __fmul_rn(__fmul_rn(dx, dy), dz);
  }
  __syncthreads();
  int i = iblk * 64 + tid;
  if (i >= PRE) return;
  u64 bits = 0;
  if (j0 + 63 > i) {
    const float* rb = boxes + ((size_t)b * PRE + i) * 6;
    float l0 = rb[0], l1 = rb[1], l2 = rb[2], h0 = rb[3], h1 = rb[4], h2 = rb[5];
    float dx = fmaxf(__fsub_rn(h0, l0), 0.0f);
    float dy = fmaxf(__fsub_rn(h1, l1), 0.0f);
    float dz = fmaxf(__fsub_rn(h2, l2), 0.0f);
    float vi = __fmul_rn(__fmul_rn(dx, dy), dz);
    for (int c = 0; c < 64; ++c) {
      int j = j0 + c;
      if (j > i && j < PRE) {
        float ix = fmaxf(__fsub_rn(fminf(h0, cb[c][3]), fmaxf(l0, cb[c][0])), 0.0f);
        float iy = fmaxf(__fsub_rn(fminf(h1, cb[c][4]), fmaxf(l1, cb[c][1])), 0.0f);
        float iz = fmaxf(__fsub_rn(fminf(h2, cb[c][5]), fmaxf(l2, cb[c][2])), 0.0f);
        float iv = __fmul_rn(__fmul_rn(ix, iy), iz);
        float un = fmaxf(__fsub_rn(__fadd_rn(vi, cb[c][6]), iv), 1e-8f);
        float iou = __fdiv_rn(iv, un);
        if (iou > 0.7f) bits |= (1ull << c);
      }
    }
  }
  masks[((size_t)b * PRE + i) * MROW + jblk] = bits;
  if (iblk == jblk) diag[((size_t)b * NW + jblk) * 64 + tid] = bits;
}

/* ---------- 9. single-wave NMS scan, kept-rows-only, zero barriers ----------
 * lane w owns rem word w (registers). Per 64-box chunk:
 *  - ff1 resolve over pending using prefetched diag (readlanes off-chain)
 *  - emit kept
 *  - per kept row: 2x global_load_lds (size=4) -> 512B LDS slot (coalesced)
 *  - ONE vmcnt(0) drain per chunk (after resolve+issue work)
 *  - ds_read_b64 slots, OR into rem
 * No barriers, no LDS atomics, ~10KB/chunk loaded (kept rows only).
 */
__global__ __launch_bounds__(64) void k_scan(const u64* __restrict__ masks,
                                             const u64* __restrict__ diag,
                                             u32* __restrict__ kept,
                                             u32* __restrict__ info) {
  __shared__ char slots[2][64 * 512];                   /* 64KB DMA landing */
  int b = blockIdx.x;
  int lane = threadIdx.x;                               /* 64 */
  const char* Mb = (const char*)masks + (size_t)b * PRE * MROW * 8;
  const u64* Db = diag + (size_t)b * NW * 64;
  u64 rem = 0;                                          /* lane w: removed bits of chunk w */
  int cnt = 0;

  u64 dc = Db[lane];                                    /* diag chunk 0 */
  u32 dlo = (u32)dc, dhi = (u32)(dc >> 32);

  for (int c = 0; c < NW; ++c) {
    int base = c * 64;
    int nrow = (base + 64 <= PRE) ? 64 : (PRE - base);

    /* prefetch next diag chunk (plain load, consumed next iter) */
    u64 dn = 0;
    if (c + 1 < NW) dn = Db[(size_t)(c + 1) * 64 + lane];

    /* pending = ~rem[c] broadcast, clipped */
    u32 rlo = __shfl((u32)rem, c);
    u32 rhi = __shfl((u32)(rem >> 32), c);
    u64 pending = ~(((u64)rhi << 32) | (u64)rlo);
    if (nrow < 64) pending &= ((1ull << nrow) - 1ull);

    /* ff1 resolve: one iteration per KEPT box */
    u64 keep = 0;
    while (pending) {
      int k = __builtin_ctzll(pending);
      keep |= (1ull << k);
      u32 rl = (u32)__builtin_amdgcn_readlane((int)dlo, k);
      u32 rh = (u32)__builtin_amdgcn_readlane((int)dhi, k);
      pending &= ~((((u64)rh << 32) | (u64)rl) | (1ull << k));
    }

    /* emit kept indices in ascending order */
    u64 ltmask = (lane == 0) ? 0ull : (~0ull >> (64 - lane));
    int pos = __popcll(keep & ltmask);
    if ((keep >> lane) & 1ull) kept[b * PRE + cnt + pos] = (u32)(base + lane);
    cnt += (int)__popcll(keep);

    /* DMA kept rows into LDS slots (coalesced 512B per row, 2 instrs) */
    char* buf = &slots[c & 1][0];
    {
      u64 kk = keep; int s = 0;
      while (kk) {
        int k = __builtin_ctzll(kk); kk &= kk - 1;
        const char* src = Mb + (size_t)(base + k) * (MROW * 8);
        __builtin_amdgcn_global_load_lds(
            (const __attribute__((address_space(1))) void*)(src + lane * 4),
            (__attribute__((address_space(3))) void*)(buf + s * 512), 4, 0, 0);
        __builtin_amdgcn_global_load_lds(
            (const __attribute__((address_space(1))) void*)(src + 256 + lane * 4),
            (__attribute__((address_space(3))) void*)(buf + s * 512 + 256), 4, 0, 0);
        ++s;
      }
    }
    asm volatile("s_waitcnt vmcnt(0)" ::: "memory");

    /* OR kept rows (lane w reads word w of each slot) into rem */
    {
      const u64* S = (const u64*)&slots[c & 1][0];
      u64 kk = keep; int s = 0; u64 acc = 0;
      while (kk) {
        kk &= kk - 1;
        acc |= S[s * 64 + lane];
        ++s;
      }
      rem |= acc;
    }

    dlo = (u32)dn; dhi = (u32)(dn >> 32);
  }
  if (lane == 0) info[16 + b] = (u32)cnt;
}

/* ---------- 10. output assembly ---------- */
__global__ void k_out(const float* __restrict__ boxes, const float* __restrict__ scoresel,
                      const u32* __restrict__ kept, const u32* __restrict__ info,
                      float* __restrict__ out) {
  int b = blockIdx.x, tid = threadIdx.x;                /* 256 */
  int cnt = (int)info[16 + b]; if (cnt > MAXOUT) cnt = MAXOUT;
  for (int k = tid; k < MAXOUT; k += 256) {
    float pr[6] = {0.f, 0.f, 0.f, 0.f, 0.f, 0.f};
    float s = 0.f, v = 0.f;
    if (k < cnt) {
      u32 i = kept[b * PRE + k];
      const float* bx = boxes + ((size_t)b * PRE + i) * 6;
#pragma unroll
      for (int d = 0; d < 6; ++d) pr[d] = bx[d];
      s = scoresel[b * PRE + i];
      v = 1.f;
    }
    float* pp = out + ((size_t)(b * MAXOUT + k)) * 6;
#pragma unroll
    for (int d = 0; d < 6; ++d) pp[d] = pr[d];
    out[BATCH * MAXOUT * 6 + b * MAXOUT + k] = s;
    out[BATCH * MAXOUT * 7 + b * MAXOUT + k] = (float)b;
    out[BATCH * MAXOUT * 8 + b * MAXOUT + k] = v;
  }
}

extern "C" void kernel_launch(void* const* d_in, const int* in_sizes, int n_in,
                              void* d_out, int out_size, void* d_ws, size_t ws_size,
                              hipStream_t stream) {
  const float* anchors = (const float*)d_in[0];
  const float* scores  = (const float*)d_in[1];
  const float* deltas  = (const float*)d_in[2];
  float* out = (float*)d_out;

  char* w = (char*)d_ws;
  u32* hist1   = (u32*)(w + OFF_HIST1);
  u32* hist2   = (u32*)(w + OFF_HIST2);
  u64* diag    = (u64*)(w + OFF_DIAG);
  u32* info    = (u32*)(w + OFF_INFO);
  u32* bcnt    = (u32*)(w + OFF_BCNT);
  u64* cand    = (u64*)(w + OFF_CAND);
  u32* order   = (u32*)(w + OFF_ORDER);
  float* scoresel = (float*)(w + OFF_SCORE);
  float* boxes = (float*)(w + OFF_BOXES);
  u64* masks   = (u64*)(w + OFF_MASKS);
  u32* kept    = (u32*)(w + OFF_KEPT);

  hipMemsetAsync(d_ws, 0, MEMSET_BYTES, stream);

  int nElem = BATCH * ANUM;
  k_hist1<<<nElem / 256, 256, 0, stream>>>(scores, hist1);
  k_sel1<<<BATCH, 256, 0, stream>>>(hist1, info);
  k_hist2<<<nElem / 256, 256, 0, stream>>>(scores, info, hist2);
  k_sel2<<<BATCH, 256, 0, stream>>>(hist2, info);
  k_compact<<<nElem / 256, 256, 0, stream>>>(scores, info, bcnt, cand);
  k_sort<<<BATCH, 1024, 0, stream>>>(cand, bcnt, order, scoresel);
  k_regress<<<(BATCH * PRE + 255) / 256, 256, 0, stream>>>(anchors, deltas, order, boxes);
  k_mask<<<dim3(NW, NW, BATCH), 64, 0, stream>>>(boxes, masks, diag);
  k_scan<<<BATCH, 64, 0, stream>>>(masks, diag, kept, info);
  k_out<<<BATCH, 256, 0, stream>>>(boxes, scoresel, kept, info, out);
}

// Round 9
// 252.050 us; speedup vs baseline: 2.8727x; 2.8727x over previous
//
#include <hip/hip_runtime.h>
#include <hip/hip_bf16.h>
#include <cstdint>

typedef unsigned int u32;
typedef unsigned long long u64;

#define ANUM 131072
#define BATCH 4
#define PRE 3000
#define CAP 4096
#define NW 47          /* ceil(3000/64) */
#define MROW 48        /* padded u64 words per mask row */
#define MAXOUT 1000
#define NBUCK 64       /* candidate buckets per batch */
#define BCAP 256       /* slots per bucket */

/* ---- workspace layout (bytes) ----
 * cand aliases hist1 (dead after k_sel1); diag aliases hist2 (dead after k_sel2)
 */
#define OFF_CAND   0ul                 /* u64[B][NBUCK][BCAP] = 512KB (aliases hist1) */
#define OFF_HIST1  0ul                 /* u32[B][65536] = 1MB */
#define OFF_HIST2  1048576ul           /* u32[B][65536] = 1MB */
#define OFF_DIAG   1048576ul           /* u64[B][NW][64] = 96256 (aliases hist2) */
#define OFF_INFO   2097152ul           /* u32[256] = 1KB */
#define OFF_ROWNZ  2098176ul           /* u64[B][NW] = 1504 -> pad 2KB */
#define OFF_BCNT   2100224ul           /* u32[B*NBUCK*16] = 16KB */
#define OFF_ORDER  2116608ul           /* u32[B][PRE] */
#define OFF_SCORE  2164608ul           /* f32[B][PRE] */
#define OFF_BOXES  2212608ul           /* f32[B][PRE][6] */
#define OFF_MASKS  2500608ul           /* u64[B][PRE][MROW] = 4608000 */
#define OFF_KEPT   7108608ul           /* u32[B][PRE] -> end 7156608 */
#define MEMSET_BYTES 2116608ul         /* hists + info + rownz + bcnt */

__device__ __forceinline__ u32 score_key(float f) {
  u32 u = __float_as_uint(f);
  return (u & 0x80000000u) ? ~u : (u | 0x80000000u);
}

/* ---------- 1. histogram of top 16 bits ---------- */
__global__ void k_hist1(const float* __restrict__ scores, u32* __restrict__ hist) {
  int t = blockIdx.x * blockDim.x + threadIdx.x;
  int b = t >> 17;
  u32 key = score_key(scores[t]);
  atomicAdd(&hist[(b << 16) + (key >> 16)], 1u);
}

/* ---------- 2. find high-16 bin crossing rank 3000 ---------- */
__global__ void k_sel1(const u32* __restrict__ hist, u32* __restrict__ info) {
  int b = blockIdx.x, tid = threadIdx.x;              /* 256 threads */
  __shared__ u32 part[256];
  const u32* h = hist + (b << 16);
  u32 s = 0;
  for (int r = tid * 256; r < tid * 256 + 256; ++r) s += h[65535 - r];
  part[tid] = s;
  __syncthreads();
  if (tid == 0) {
    u32 c = 0; int tstar = 0; u32 cb = 0;
    for (int t = 0; t < 256; ++t) {
      if (c + part[t] >= PRE) { tstar = t; cb = c; break; }
      c += part[t];
    }
    u32 cc = cb; int b16 = 0;
    for (int r = tstar * 256; r < 65536; ++r) {
      u32 cnt = h[65535 - r];
      if (cc + cnt >= PRE) { b16 = 65535 - r; break; }
      cc += cnt;
    }
    info[b] = (u32)b16;
    info[4 + b] = cc;
  }
}

/* ---------- 3. histogram of low 16 bits within the boundary bin ---------- */
__global__ void k_hist2(const float* __restrict__ scores, const u32* __restrict__ info,
                        u32* __restrict__ hist2) {
  int t = blockIdx.x * blockDim.x + threadIdx.x;
  int b = t >> 17;
  u32 key = score_key(scores[t]);
  if ((key >> 16) == info[b])
    atomicAdd(&hist2[(b << 16) + (key & 0xFFFFu)], 1u);
}

/* ---------- 4. exact threshold key T ---------- */
__global__ void k_sel2(const u32* __restrict__ hist2, u32* __restrict__ info) {
  int b = blockIdx.x, tid = threadIdx.x;
  __shared__ u32 part[256];
  const u32* h = hist2 + (b << 16);
  u32 s = 0;
  for (int r = tid * 256; r < tid * 256 + 256; ++r) s += h[65535 - r];
  part[tid] = s;
  __syncthreads();
  if (tid == 0) {
    int target = PRE - (int)info[4 + b];
    u32 c = 0; int tstar = 0; u32 cb = 0;
    for (int t = 0; t < 256; ++t) {
      if ((int)(c + part[t]) >= target) { tstar = t; cb = c; break; }
      c += part[t];
    }
    u32 cc = cb; int t16 = 0;
    for (int r = tstar * 256; r < 65536; ++r) {
      u32 cnt = h[65535 - r];
      if ((int)(cc + cnt) >= target) { t16 = 65535 - r; break; }
      cc += cnt;
    }
    info[8 + b] = (info[b] << 16) | (u32)t16;
  }
}

/* ---------- 5. compact candidates (key >= T) into per-bucket lists ---------- */
__global__ void k_compact(const float* __restrict__ scores, const u32* __restrict__ info,
                          u32* __restrict__ bcnt, u64* __restrict__ cand) {
  int t = blockIdx.x * blockDim.x + threadIdx.x;
  int b = t >> 17;
  int e = t & (ANUM - 1);
  int bucket = (blockIdx.x >> 3) & (NBUCK - 1);
  u32 key = score_key(scores[t]);
  if (key >= info[8 + b]) {
    u32 pos = atomicAdd(&bcnt[(u32)((b << 6) + bucket) * 16u], 1u);
    if (pos < BCAP) cand[(size_t)((b << 6) + bucket) * BCAP + pos] = ((u64)key << 32) | (u32)(~(u32)e);
  }
}

/* ---------- 6. gather buckets + bitonic sort (descending) ---------- */
__global__ __launch_bounds__(1024) void k_sort(const u64* __restrict__ cand,
                                               const u32* __restrict__ bcnt,
                                               u32* __restrict__ order,
                                               float* __restrict__ scoresel) {
  int b = blockIdx.x, tid = threadIdx.x;
  __shared__ u64 s[CAP];
  __shared__ u32 pref[NBUCK + 1];
  if (tid < NBUCK) {
    u32 c = bcnt[(u32)((b << 6) + tid) * 16u];
    if (c > BCAP) c = BCAP;
    u32 inc = c;
#pragma unroll
    for (int d = 1; d < 64; d <<= 1) {
      u32 v = __shfl_up(inc, d);
      if (tid >= d) inc += v;
    }
    pref[tid + 1] = inc;
    if (tid == 0) pref[0] = 0;
  }
  __syncthreads();
  for (int i = tid; i < CAP; i += 1024) s[i] = 0ull;
  __syncthreads();
  for (int j = tid; j < NBUCK * BCAP; j += 1024) {
    int bk = j >> 8, sl = j & (BCAP - 1);
    u32 c = pref[bk + 1] - pref[bk];
    if ((u32)sl < c) s[pref[bk] + sl] = cand[(size_t)((b << 6) + bk) * BCAP + sl];
  }
  __syncthreads();
  for (int k = 2; k <= CAP; k <<= 1) {
    for (int j = k >> 1; j > 0; j >>= 1) {
      for (int i = tid; i < CAP; i += 1024) {
        int ixj = i ^ j;
        if (ixj > i) {
          u64 a = s[i], c = s[ixj];
          bool up = ((i & k) == 0);
          if (up ? (a < c) : (a > c)) { s[i] = c; s[ixj] = a; }
        }
      }
      __syncthreads();
    }
  }
  for (int i = tid; i < PRE; i += 1024) {
    u64 kv = s[i];
    u32 key = (u32)(kv >> 32);
    u32 e = ~((u32)kv);
    order[b * PRE + i] = e;
    u32 u = (key & 0x80000000u) ? (key ^ 0x80000000u) : ~key;
    scoresel[b * PRE + i] = __uint_as_float(u);
  }
}

/* ---------- 7. gather + box regression ---------- */
__global__ void k_regress(const float* __restrict__ anchors, const float* __restrict__ deltas,
                          const u32* __restrict__ order, float* __restrict__ boxes) {
  int t = blockIdx.x * blockDim.x + threadIdx.x;
  if (t >= BATCH * PRE) return;
  int b = t / PRE;
  u32 a = order[t];
  const float* an = anchors + (size_t)a * 6;
  const float* de = deltas + ((size_t)b * ANUM + a) * 6;
  float* out = boxes + (size_t)t * 6;
#pragma unroll
  for (int d = 0; d < 3; ++d) {
    float lo = an[d], hi = an[3 + d];
    float dims = __fsub_rn(hi, lo);
    float ctr = __fadd_rn(lo, __fmul_rn(0.5f, dims));
    ctr = __fadd_rn(ctr, __fmul_rn(de[d], dims));
    float nd = __fmul_rn(dims, expf(de[3 + d]));
    float h = __fmul_rn(0.5f, nd);
    out[d] = __fsub_rn(ctr, h);
    out[3 + d] = __fadd_rn(ctr, h);
  }
}

/* ---------- 8. suppression bitmask matrix (+ diag blocks + row-NZ bitmap) ---------- */
__global__ void k_mask(const float* __restrict__ boxes, u64* __restrict__ masks,
                       u64* __restrict__ diag, u64* __restrict__ rownz) {
  int jblk = blockIdx.x, iblk = blockIdx.y, b = blockIdx.z;
  int tid = threadIdx.x;                                /* 64 */
  __shared__ float cb[64][7];
  int j0 = jblk * 64;
  {
    int jj = j0 + tid; if (jj > PRE - 1) jj = PRE - 1;
    const float* src = boxes + ((size_t)b * PRE + jj) * 6;
#pragma unroll
    for (int d = 0; d < 6; ++d) cb[tid][d] = src[d];
    float dx = fmaxf(__fsub_rn(cb[tid][3], cb[tid][0]), 0.0f);
    float dy = fmaxf(__fsub_rn(cb[tid][4], cb[tid][1]), 0.0f);
    float dz = fmaxf(__fsub_rn(cb[tid][5], cb[tid][2]), 0.0f);
    cb[tid][6] = __fmul_rn(__fmul_rn(dx, dy), dz);
  }
  __syncthreads();
  int i = iblk * 64 + tid;
  if (i >= PRE) return;
  u64 bits = 0;
  if (j0 + 63 > i) {
    const float* rb = boxes + ((size_t)b * PRE + i) * 6;
    float l0 = rb[0], l1 = rb[1], l2 = rb[2], h0 = rb[3], h1 = rb[4], h2 = rb[5];
    float dx = fmaxf(__fsub_rn(h0, l0), 0.0f);
    float dy = fmaxf(__fsub_rn(h1, l1), 0.0f);
    float dz = fmaxf(__fsub_rn(h2, l2), 0.0f);
    float vi = __fmul_rn(__fmul_rn(dx, dy), dz);
    for (int c = 0; c < 64; ++c) {
      int j = j0 + c;
      if (j > i && j < PRE) {
        float ix = fmaxf(__fsub_rn(fminf(h0, cb[c][3]), fmaxf(l0, cb[c][0])), 0.0f);
        float iy = fmaxf(__fsub_rn(fminf(h1, cb[c][4]), fmaxf(l1, cb[c][1])), 0.0f);
        float iz = fmaxf(__fsub_rn(fminf(h2, cb[c][5]), fmaxf(l2, cb[c][2])), 0.0f);
        float iv = __fmul_rn(__fmul_rn(ix, iy), iz);
        float un = fmaxf(__fsub_rn(__fadd_rn(vi, cb[c][6]), iv), 1e-8f);
        float iou = __fdiv_rn(iv, un);
        if (iou > 0.7f) bits |= (1ull << c);
      }
    }
  }
  masks[((size_t)b * PRE + i) * MROW + jblk] = bits;
  if (iblk == jblk) diag[((size_t)b * NW + jblk) * 64 + tid] = bits;
  /* row-nonzero bitmap: bit i of rownz[b][iblk] = (row i has any suppression
     bit in columns of this jblk). OR across jblk via atomic. */
  u64 bal = __ballot(bits != 0ull);
  if (tid == 0 && bal) atomicOr(&rownz[b * NW + iblk], bal);
}

/* ---------- 9. sparse single-wave NMS scan ----------
 * lane w owns rem word w in a register. Exploits mask sparsity EXACTLY:
 *  - intra-chunk ff1 chain only over alive boxes with NONZERO diag row
 *    (zero-row boxes are kept-if-alive and affect nobody)
 *  - propagation loads only kept rows flagged nonzero in rownz (batched 8-wide,
 *    loads off the scalar chain)
 *  - early uniform break once cnt >= MAXOUT (emit is ascending; k_out reads
 *    only first MAXOUT)
 * Zero barriers, zero LDS, worst case degrades to dense-row behavior.
 */
__global__ __launch_bounds__(64) void k_scan(const u64* __restrict__ masks,
                                             const u64* __restrict__ diag,
                                             const u64* __restrict__ rownz,
                                             u32* __restrict__ kept,
                                             u32* __restrict__ info) {
  int b = blockIdx.x;
  int lane = threadIdx.x;                               /* 64 */
  const u64* Mb = masks + (size_t)b * PRE * MROW;
  const u64* Db = diag + (size_t)b * NW * 64;
  const u64* Nb = rownz + b * NW;
  int wl = lane < NW ? lane : NW - 1;
  u64 rem = 0;                                          /* lane w: removed bits of chunk w */
  int cnt = 0;

  u64 dcur = Db[lane];                                  /* diag chunk 0 */

  for (int c = 0; c < NW; ++c) {
    int base = c * 64;
    int nrow = (base + 64 <= PRE) ? 64 : (PRE - base);

    /* prefetch next diag chunk */
    u64 dn = (c + 1 < NW) ? Db[(size_t)(c + 1) * 64 + lane] : 0ull;
    u64 nzc = Nb[c];                                    /* uniform scalar load */

    /* pending = ~rem[c] broadcast, clipped */
    u32 rlo = __shfl((u32)rem, c);
    u32 rhi = __shfl((u32)(rem >> 32), c);
    u64 pending = ~(((u64)rhi << 32) | (u64)rlo);
    if (nrow < 64) pending &= ((1ull << nrow) - 1ull);

    /* intra resolve: only alive boxes whose diag row is nonzero matter */
    u64 Z = __ballot(dcur != 0ull);
    u64 chain = pending & Z;
    while (chain) {
      int k = __builtin_ctzll(chain);
      u32 rl = (u32)__builtin_amdgcn_readlane((int)(u32)dcur, k);
      u32 rh = (u32)__builtin_amdgcn_readlane((int)(u32)(dcur >> 32), k);
      u64 rw = ((u64)rh << 32) | (u64)rl;
      pending &= ~rw;                                   /* k keeps its own bit */
      chain &= pending;
      chain &= ~(1ull << k);
    }
    u64 keep = pending;

    /* emit kept indices in ascending order */
    u64 ltmask = (lane == 0) ? 0ull : (~0ull >> (64 - lane));
    int pos = __popcll(keep & ltmask);
    if ((keep >> lane) & 1ull) kept[b * PRE + cnt + pos] = (u32)(base + lane);
    cnt += (int)__popcll(keep);

    if (cnt >= MAXOUT) break;                           /* uniform; rest is dead work */

    /* propagate kept rows that have any suppression bits (batched 8-wide) */
    u64 nz = keep & nzc;
    while (nz) {
      int rks[8]; int m = 0; int rr = base;
#pragma unroll
      for (int s = 0; s < 8; ++s) {
        if (nz) { rr = base + __builtin_ctzll(nz); nz &= nz - 1; ++m; }
        rks[s] = rr;
      }
      u64 v[8];
#pragma unroll
      for (int s = 0; s < 8; ++s) v[s] = Mb[(size_t)rks[s] * MROW + wl];
      u64 acc = 0;
#pragma unroll
      for (int s = 0; s < 8; ++s) acc |= (s < m) ? v[s] : 0ull;
      rem |= acc;
    }

    dcur = dn;
  }
  if (lane == 0) info[16 + b] = (u32)cnt;
}

/* ---------- 10. output assembly ---------- */
__global__ void k_out(const float* __restrict__ boxes, const float* __restrict__ scoresel,
                      const u32* __restrict__ kept, const u32* __restrict__ info,
                      float* __restrict__ out) {
  int b = blockIdx.x, tid = threadIdx.x;                /* 256 */
  int cnt = (int)info[16 + b]; if (cnt > MAXOUT) cnt = MAXOUT;
  for (int k = tid; k < MAXOUT; k += 256) {
    float pr[6] = {0.f, 0.f, 0.f, 0.f, 0.f, 0.f};
    float s = 0.f, v = 0.f;
    if (k < cnt) {
      u32 i = kept[b * PRE + k];
      const float* bx = boxes + ((size_t)b * PRE + i) * 6;
#pragma unroll
      for (int d = 0; d < 6; ++d) pr[d] = bx[d];
      s = scoresel[b * PRE + i];
      v = 1.f;
    }
    float* pp = out + ((size_t)(b * MAXOUT + k)) * 6;
#pragma unroll
    for (int d = 0; d < 6; ++d) pp[d] = pr[d];
    out[BATCH * MAXOUT * 6 + b * MAXOUT + k] = s;
    out[BATCH * MAXOUT * 7 + b * MAXOUT + k] = (float)b;
    out[BATCH * MAXOUT * 8 + b * MAXOUT + k] = v;
  }
}

extern "C" void kernel_launch(void* const* d_in, const int* in_sizes, int n_in,
                              void* d_out, int out_size, void* d_ws, size_t ws_size,
                              hipStream_t stream) {
  const float* anchors = (const float*)d_in[0];
  const float* scores  = (const float*)d_in[1];
  const float* deltas  = (const float*)d_in[2];
  float* out = (float*)d_out;

  char* w = (char*)d_ws;
  u32* hist1   = (u32*)(w + OFF_HIST1);
  u32* hist2   = (u32*)(w + OFF_HIST2);
  u64* diag    = (u64*)(w + OFF_DIAG);
  u64* rownz   = (u64*)(w + OFF_ROWNZ);
  u32* info    = (u32*)(w + OFF_INFO);
  u32* bcnt    = (u32*)(w + OFF_BCNT);
  u64* cand    = (u64*)(w + OFF_CAND);
  u32* order   = (u32*)(w + OFF_ORDER);
  float* scoresel = (float*)(w + OFF_SCORE);
  float* boxes = (float*)(w + OFF_BOXES);
  u64* masks   = (u64*)(w + OFF_MASKS);
  u32* kept    = (u32*)(w + OFF_KEPT);

  hipMemsetAsync(d_ws, 0, MEMSET_BYTES, stream);

  int nElem = BATCH * ANUM;
  k_hist1<<<nElem / 256, 256, 0, stream>>>(scores, hist1);
  k_sel1<<<BATCH, 256, 0, stream>>>(hist1, info);
  k_hist2<<<nElem / 256, 256, 0, stream>>>(scores, info, hist2);
  k_sel2<<<BATCH, 256, 0, stream>>>(hist2, info);
  k_compact<<<nElem / 256, 256, 0, stream>>>(scores, info, bcnt, cand);
  k_sort<<<BATCH, 1024, 0, stream>>>(cand, bcnt, order, scoresel);
  k_regress<<<(BATCH * PRE + 255) / 256, 256, 0, stream>>>(anchors, deltas, order, boxes);
  k_mask<<<dim3(NW, NW, BATCH), 64, 0, stream>>>(boxes, masks, diag, rownz);
  k_scan<<<BATCH, 64, 0, stream>>>(masks, diag, rownz, kept, info);
  k_out<<<BATCH, 256, 0, stream>>>(boxes, scoresel, kept, info, out);
}

// Round 10
// 239.206 us; speedup vs baseline: 3.0270x; 1.0537x over previous
//
#include <hip/hip_runtime.h>
#include <hip/hip_bf16.h>
#include <cstdint>

typedef unsigned int u32;
typedef unsigned long long u64;

#define ANUM 131072
#define BATCH 4
#define PRE 3000
#define CAP 4096
#define NW 47          /* ceil(3000/64) */
#define MROW 48        /* padded u64 words per mask row */
#define MAXOUT 1000
#define NBUCK 64       /* candidate buckets per batch */
#define BCAP 256       /* slots per bucket */

/* ---- workspace layout (bytes) ----
 * cand aliases hist1 (dead after k_sel1); diag+dense alias hist2 (dead after k_sel2)
 */
#define OFF_CAND   0ul                 /* u64[B][NBUCK][BCAP] = 512KB (aliases hist1) */
#define OFF_HIST1  0ul                 /* u32[B][65536] = 1MB */
#define OFF_HIST2  1048576ul           /* u32[B][65536] = 1MB */
#define OFF_DIAG   1048576ul           /* u64[B][NW][64] = 96256 (aliases hist2) */
#define OFF_DENSE  1179648ul           /* u64[B][CAP] = 131072 (aliases hist2 tail) */
#define OFF_INFO   2097152ul           /* u32[256] = 1KB; [20..23]=totals */
#define OFF_ROWNZ  2098176ul           /* u64[B][NW] = 1504 -> pad 2KB */
#define OFF_BCNT   2100224ul           /* u32[B*NBUCK*16] = 16KB */
#define OFF_ORDER  2116608ul           /* u32[B][PRE] */
#define OFF_SCORE  2164608ul           /* f32[B][PRE] */
#define OFF_BOXES  2212608ul           /* f32[B][PRE][6] */
#define OFF_MASKS  2500608ul           /* u64[B][PRE][MROW] = 4608000 */
#define OFF_KEPT   7108608ul           /* u32[B][PRE] -> end 7156608 */
#define MEMSET_BYTES 2116608ul         /* hists + info + rownz + bcnt */

__device__ __forceinline__ u32 score_key(float f) {
  u32 u = __float_as_uint(f);
  return (u & 0x80000000u) ? ~u : (u | 0x80000000u);
}

/* ---------- 1. histogram of top 16 bits ---------- */
__global__ void k_hist1(const float* __restrict__ scores, u32* __restrict__ hist) {
  int t = blockIdx.x * blockDim.x + threadIdx.x;
  int b = t >> 17;
  u32 key = score_key(scores[t]);
  atomicAdd(&hist[(b << 16) + (key >> 16)], 1u);
}

/* ---------- 2. find high-16 bin crossing rank 3000 ---------- */
__global__ void k_sel1(const u32* __restrict__ hist, u32* __restrict__ info) {
  int b = blockIdx.x, tid = threadIdx.x;              /* 256 threads */
  __shared__ u32 part[256];
  const u32* h = hist + (b << 16);
  u32 s = 0;
  for (int r = tid * 256; r < tid * 256 + 256; ++r) s += h[65535 - r];
  part[tid] = s;
  __syncthreads();
  if (tid == 0) {
    u32 c = 0; int tstar = 0; u32 cb = 0;
    for (int t = 0; t < 256; ++t) {
      if (c + part[t] >= PRE) { tstar = t; cb = c; break; }
      c += part[t];
    }
    u32 cc = cb; int b16 = 0;
    for (int r = tstar * 256; r < 65536; ++r) {
      u32 cnt = h[65535 - r];
      if (cc + cnt >= PRE) { b16 = 65535 - r; break; }
      cc += cnt;
    }
    info[b] = (u32)b16;
    info[4 + b] = cc;
  }
}

/* ---------- 3. histogram of low 16 bits within the boundary bin ---------- */
__global__ void k_hist2(const float* __restrict__ scores, const u32* __restrict__ info,
                        u32* __restrict__ hist2) {
  int t = blockIdx.x * blockDim.x + threadIdx.x;
  int b = t >> 17;
  u32 key = score_key(scores[t]);
  if ((key >> 16) == info[b])
    atomicAdd(&hist2[(b << 16) + (key & 0xFFFFu)], 1u);
}

/* ---------- 4. exact threshold key T ---------- */
__global__ void k_sel2(const u32* __restrict__ hist2, u32* __restrict__ info) {
  int b = blockIdx.x, tid = threadIdx.x;
  __shared__ u32 part[256];
  const u32* h = hist2 + (b << 16);
  u32 s = 0;
  for (int r = tid * 256; r < tid * 256 + 256; ++r) s += h[65535 - r];
  part[tid] = s;
  __syncthreads();
  if (tid == 0) {
    int target = PRE - (int)info[4 + b];
    u32 c = 0; int tstar = 0; u32 cb = 0;
    for (int t = 0; t < 256; ++t) {
      if ((int)(c + part[t]) >= target) { tstar = t; cb = c; break; }
      c += part[t];
    }
    u32 cc = cb; int t16 = 0;
    for (int r = tstar * 256; r < 65536; ++r) {
      u32 cnt = h[65535 - r];
      if ((int)(cc + cnt) >= target) { t16 = 65535 - r; break; }
      cc += cnt;
    }
    info[8 + b] = (info[b] << 16) | (u32)t16;
  }
}

/* ---------- 5. compact candidates (key >= T) into per-bucket lists ---------- */
__global__ void k_compact(const float* __restrict__ scores, const u32* __restrict__ info,
                          u32* __restrict__ bcnt, u64* __restrict__ cand) {
  int t = blockIdx.x * blockDim.x + threadIdx.x;
  int b = t >> 17;
  int e = t & (ANUM - 1);
  int bucket = (blockIdx.x >> 3) & (NBUCK - 1);
  u32 key = score_key(scores[t]);
  if (key >= info[8 + b]) {
    u32 pos = atomicAdd(&bcnt[(u32)((b << 6) + bucket) * 16u], 1u);
    if (pos < BCAP) cand[(size_t)((b << 6) + bucket) * BCAP + pos] = ((u64)key << 32) | (u32)(~(u32)e);
  }
}

/* ---------- 6a. gather buckets into dense zero-padded list ---------- */
__global__ __launch_bounds__(1024) void k_gather(const u64* __restrict__ cand,
                                                 const u32* __restrict__ bcnt,
                                                 u64* __restrict__ dense,
                                                 u32* __restrict__ info) {
  int b = blockIdx.x, tid = threadIdx.x;
  __shared__ u32 pref[NBUCK + 1];
  if (tid < NBUCK) {                                   /* wave 0: scan bucket counts */
    u32 c = bcnt[(u32)((b << 6) + tid) * 16u];
    if (c > BCAP) c = BCAP;
    u32 inc = c;
#pragma unroll
    for (int d = 1; d < 64; d <<= 1) {
      u32 v = __shfl_up(inc, d);
      if (tid >= d) inc += v;
    }
    pref[tid + 1] = inc;
    if (tid == 0) pref[0] = 0;
  }
  __syncthreads();
  u32 total = pref[NBUCK]; if (total > CAP) total = CAP;
  if (tid == 0) info[20 + b] = total;
  for (int i = tid; i < CAP; i += 1024) dense[b * CAP + i] = 0ull;
  __syncthreads();                                     /* order zero-pad vs gather writes */
  for (int j = tid; j < NBUCK * BCAP; j += 1024) {
    int bk = j >> 8, sl = j & (BCAP - 1);
    u32 c = pref[bk + 1] - pref[bk];
    u32 pos = pref[bk] + (u32)sl;
    if ((u32)sl < c && pos < CAP) dense[b * CAP + pos] = cand[(size_t)((b << 6) + bk) * BCAP + sl];
  }
}

/* ---------- 6b. rank-by-counting (replaces bitonic sort) ----------
 * Unique 64-bit keys -> rank i = #{j: key_j > key_i} is a permutation of
 * [0,total). Emit order/scoresel at slot rank if rank < PRE. Zero-padded
 * slots never count (valid keys have low32 != 0 -> key64 > 0).
 */
__global__ __launch_bounds__(256) void k_rank(const u64* __restrict__ dense,
                                              const u32* __restrict__ info,
                                              u32* __restrict__ order,
                                              float* __restrict__ scoresel) {
  int b = blockIdx.y;
  int tid = threadIdx.x;
  int i = blockIdx.x * 256 + tid;
  __shared__ u64 tile[256];
  u64 mykey = dense[(size_t)b * CAP + i];
  int ntile = ((int)info[20 + b] + 255) >> 8;
  int rank = 0;
  for (int t = 0; t < ntile; ++t) {
    tile[tid] = dense[(size_t)b * CAP + t * 256 + tid];
    __syncthreads();
#pragma unroll 8
    for (int j = 0; j < 256; ++j) rank += (tile[j] > mykey) ? 1 : 0;
    __syncthreads();
  }
  if ((u32)mykey != 0u && rank < PRE) {
    u32 key = (u32)(mykey >> 32);
    u32 e = ~((u32)mykey);
    order[b * PRE + rank] = e;
    u32 u = (key & 0x80000000u) ? (key ^ 0x80000000u) : ~key;
    scoresel[b * PRE + rank] = __uint_as_float(u);
  }
}

/* ---------- 7. gather + box regression ---------- */
__global__ void k_regress(const float* __restrict__ anchors, const float* __restrict__ deltas,
                          const u32* __restrict__ order, float* __restrict__ boxes) {
  int t = blockIdx.x * blockDim.x + threadIdx.x;
  if (t >= BATCH * PRE) return;
  int b = t / PRE;
  u32 a = order[t];
  const float* an = anchors + (size_t)a * 6;
  const float* de = deltas + ((size_t)b * ANUM + a) * 6;
  float* out = boxes + (size_t)t * 6;
#pragma unroll
  for (int d = 0; d < 3; ++d) {
    float lo = an[d], hi = an[3 + d];
    float dims = __fsub_rn(hi, lo);
    float ctr = __fadd_rn(lo, __fmul_rn(0.5f, dims));
    ctr = __fadd_rn(ctr, __fmul_rn(de[d], dims));
    float nd = __fmul_rn(dims, expf(de[3 + d]));
    float h = __fmul_rn(0.5f, nd);
    out[d] = __fsub_rn(ctr, h);
    out[3 + d] = __fadd_rn(ctr, h);
  }
}

/* ---------- 8. suppression bitmask matrix (+ diag blocks + row-NZ bitmap) ---------- */
__global__ void k_mask(const float* __restrict__ boxes, u64* __restrict__ masks,
                       u64* __restrict__ diag, u64* __restrict__ rownz) {
  int jblk = blockIdx.x, iblk = blockIdx.y, b = blockIdx.z;
  int tid = threadIdx.x;                                /* 64 */
  __shared__ float cb[64][7];
  int j0 = jblk * 64;
  {
    int jj = j0 + tid; if (jj > PRE - 1) jj = PRE - 1;
    const float* src = boxes + ((size_t)b * PRE + jj) * 6;
#pragma unroll
    for (int d = 0; d < 6; ++d) cb[tid][d] = src[d];
    float dx = fmaxf(__fsub_rn(cb[tid][3], cb[tid][0]), 0.0f);
    float dy = fmaxf(__fsub_rn(cb[tid][4], cb[tid][1]), 0.0f);
    float dz = fmaxf(__fsub_rn(cb[tid][5], cb[tid][2]), 0.0f);
    cb[tid][6] = __fmul_rn(__fmul_rn(dx, dy), dz);
  }
  __syncthreads();
  int i = iblk * 64 + tid;
  if (i >= PRE) return;
  u64 bits = 0;
  if (j0 + 63 > i) {
    const float* rb = boxes + ((size_t)b * PRE + i) * 6;
    float l0 = rb[0], l1 = rb[1], l2 = rb[2], h0 = rb[3], h1 = rb[4], h2 = rb[5];
    float dx = fmaxf(__fsub_rn(h0, l0), 0.0f);
    float dy = fmaxf(__fsub_rn(h1, l1), 0.0f);
    float dz = fmaxf(__fsub_rn(h2, l2), 0.0f);
    float vi = __fmul_rn(__fmul_rn(dx, dy), dz);
    for (int c = 0; c < 64; ++c) {
      int j = j0 + c;
      if (j > i && j < PRE) {
        float ix = fmaxf(__fsub_rn(fminf(h0, cb[c][3]), fmaxf(l0, cb[c][0])), 0.0f);
        float iy = fmaxf(__fsub_rn(fminf(h1, cb[c][4]), fmaxf(l1, cb[c][1])), 0.0f);
        float iz = fmaxf(__fsub_rn(fminf(h2, cb[c][5]), fmaxf(l2, cb[c][2])), 0.0f);
        float iv = __fmul_rn(__fmul_rn(ix, iy), iz);
        float un = fmaxf(__fsub_rn(__fadd_rn(vi, cb[c][6]), iv), 1e-8f);
        float iou = __fdiv_rn(iv, un);
        if (iou > 0.7f) bits |= (1ull << c);
      }
    }
  }
  masks[((size_t)b * PRE + i) * MROW + jblk] = bits;
  if (iblk == jblk) diag[((size_t)b * NW + jblk) * 64 + tid] = bits;
  u64 bal = __ballot(bits != 0ull);
  if (tid == 0 && bal) atomicOr(&rownz[b * NW + iblk], bal);
}

/* ---------- 9. sparse single-wave NMS scan ---------- */
__global__ __launch_bounds__(64) void k_scan(const u64* __restrict__ masks,
                                             const u64* __restrict__ diag,
                                             const u64* __restrict__ rownz,
                                             u32* __restrict__ kept,
                                             u32* __restrict__ info) {
  int b = blockIdx.x;
  int lane = threadIdx.x;                               /* 64 */
  const u64* Mb = masks + (size_t)b * PRE * MROW;
  const u64* Db = diag + (size_t)b * NW * 64;
  const u64* Nb = rownz + b * NW;
  int wl = lane < NW ? lane : NW - 1;
  u64 rem = 0;
  int cnt = 0;

  u64 dcur = Db[lane];

  for (int c = 0; c < NW; ++c) {
    int base = c * 64;
    int nrow = (base + 64 <= PRE) ? 64 : (PRE - base);

    u64 dn = (c + 1 < NW) ? Db[(size_t)(c + 1) * 64 + lane] : 0ull;
    u64 nzc = Nb[c];

    u32 rlo = __shfl((u32)rem, c);
    u32 rhi = __shfl((u32)(rem >> 32), c);
    u64 pending = ~(((u64)rhi << 32) | (u64)rlo);
    if (nrow < 64) pending &= ((1ull << nrow) - 1ull);

    u64 Z = __ballot(dcur != 0ull);
    u64 chain = pending & Z;
    while (chain) {
      int k = __builtin_ctzll(chain);
      u32 rl = (u32)__builtin_amdgcn_readlane((int)(u32)dcur, k);
      u32 rh = (u32)__builtin_amdgcn_readlane((int)(u32)(dcur >> 32), k);
      u64 rw = ((u64)rh << 32) | (u64)rl;
      pending &= ~rw;
      chain &= pending;
      chain &= ~(1ull << k);
    }
    u64 keep = pending;

    u64 ltmask = (lane == 0) ? 0ull : (~0ull >> (64 - lane));
    int pos = __popcll(keep & ltmask);
    if ((keep >> lane) & 1ull) kept[b * PRE + cnt + pos] = (u32)(base + lane);
    cnt += (int)__popcll(keep);

    if (cnt >= MAXOUT) break;

    u64 nz = keep & nzc;
    while (nz) {
      int rks[8]; int m = 0; int rr = base;
#pragma unroll
      for (int s = 0; s < 8; ++s) {
        if (nz) { rr = base + __builtin_ctzll(nz); nz &= nz - 1; ++m; }
        rks[s] = rr;
      }
      u64 v[8];
#pragma unroll
      for (int s = 0; s < 8; ++s) v[s] = Mb[(size_t)rks[s] * MROW + wl];
      u64 acc = 0;
#pragma unroll
      for (int s = 0; s < 8; ++s) acc |= (s < m) ? v[s] : 0ull;
      rem |= acc;
    }

    dcur = dn;
  }
  if (lane == 0) info[16 + b] = (u32)cnt;
}

/* ---------- 10. output assembly ---------- */
__global__ void k_out(const float* __restrict__ boxes, const float* __restrict__ scoresel,
                      const u32* __restrict__ kept, const u32* __restrict__ info,
                      float* __restrict__ out) {
  int b = blockIdx.x, tid = threadIdx.x;                /* 256 */
  int cnt = (int)info[16 + b]; if (cnt > MAXOUT) cnt = MAXOUT;
  for (int k = tid; k < MAXOUT; k += 256) {
    float pr[6] = {0.f, 0.f, 0.f, 0.f, 0.f, 0.f};
    float s = 0.f, v = 0.f;
    if (k < cnt) {
      u32 i = kept[b * PRE + k];
      const float* bx = boxes + ((size_t)b * PRE + i) * 6;
#pragma unroll
      for (int d = 0; d < 6; ++d) pr[d] = bx[d];
      s = scoresel[b * PRE + i];
      v = 1.f;
    }
    float* pp = out + ((size_t)(b * MAXOUT + k)) * 6;
#pragma unroll
    for (int d = 0; d < 6; ++d) pp[d] = pr[d];
    out[BATCH * MAXOUT * 6 + b * MAXOUT + k] = s;
    out[BATCH * MAXOUT * 7 + b * MAXOUT + k] = (float)b;
    out[BATCH * MAXOUT * 8 + b * MAXOUT + k] = v;
  }
}

extern "C" void kernel_launch(void* const* d_in, const int* in_sizes, int n_in,
                              void* d_out, int out_size, void* d_ws, size_t ws_size,
                              hipStream_t stream) {
  const float* anchors = (const float*)d_in[0];
  const float* scores  = (const float*)d_in[1];
  const float* deltas  = (const float*)d_in[2];
  float* out = (float*)d_out;

  char* w = (char*)d_ws;
  u32* hist1   = (u32*)(w + OFF_HIST1);
  u32* hist2   = (u32*)(w + OFF_HIST2);
  u64* diag    = (u64*)(w + OFF_DIAG);
  u64* dense   = (u64*)(w + OFF_DENSE);
  u64* rownz   = (u64*)(w + OFF_ROWNZ);
  u32* info    = (u32*)(w + OFF_INFO);
  u32* bcnt    = (u32*)(w + OFF_BCNT);
  u64* cand    = (u64*)(w + OFF_CAND);
  u32* order   = (u32*)(w + OFF_ORDER);
  float* scoresel = (float*)(w + OFF_SCORE);
  float* boxes = (float*)(w + OFF_BOXES);
  u64* masks   = (u64*)(w + OFF_MASKS);
  u32* kept    = (u32*)(w + OFF_KEPT);

  hipMemsetAsync(d_ws, 0, MEMSET_BYTES, stream);

  int nElem = BATCH * ANUM;
  k_hist1<<<nElem / 256, 256, 0, stream>>>(scores, hist1);
  k_sel1<<<BATCH, 256, 0, stream>>>(hist1, info);
  k_hist2<<<nElem / 256, 256, 0, stream>>>(scores, info, hist2);
  k_sel2<<<BATCH, 256, 0, stream>>>(hist2, info);
  k_compact<<<nElem / 256, 256, 0, stream>>>(scores, info, bcnt, cand);
  k_gather<<<BATCH, 1024, 0, stream>>>(cand, bcnt, dense, info);
  k_rank<<<dim3(CAP / 256, BATCH), 256, 0, stream>>>(dense, info, order, scoresel);
  k_regress<<<(BATCH * PRE + 255) / 256, 256, 0, stream>>>(anchors, deltas, order, boxes);
  k_mask<<<dim3(NW, NW, BATCH), 64, 0, stream>>>(boxes, masks, diag, rownz);
  k_scan<<<BATCH, 64, 0, stream>>>(masks, diag, rownz, kept, info);
  k_out<<<BATCH, 256, 0, stream>>>(boxes, scoresel, kept, info, out);
}

// Round 11
// 151.417 us; speedup vs baseline: 4.7820x; 1.5798x over previous
//
#include <hip/hip_runtime.h>
#include <hip/hip_bf16.h>
#include <cstdint>

typedef unsigned int u32;
typedef unsigned long long u64;

#define ANUM 131072
#define BATCH 4
#define PRE 3000
#define CAP 8192       /* candidate slack: threshold is bin-floor (coarse), rank fixes order */
#define NW 47          /* ceil(3000/64) */
#define MROW 48        /* padded u64 words per mask row */
#define MAXOUT 1000
#define NBUCK 64       /* candidate buckets per batch */
#define BCAP 256       /* slots per bucket (lambda~69, overflow impossible) */
#define NSUB 16        /* histogram sub-blocks per batch */

/* ---- workspace layout (bytes) ----
 * part aliases cand (partials consumed by k_sel12 before k_compact writes cand)
 */
#define OFF_PART   0ul                 /* u32[B][4096][NSUB] = 1MB */
#define OFF_CAND   0ul                 /* u64[B][NBUCK][BCAP] = 512KB (aliases part) */
#define OFF_DIAG   1048576ul           /* u64[B][NW][64] = 96256 */
#define OFF_DENSE  1179648ul           /* u64[B][CAP] = 262144 -> ends 1441792 */
#define OFF_INFO   2097152ul           /* u32[256]: [0..3]=b12 [4..7]=cc [8..11]=T32
                                          [16..19]=keptcnt [20..23]=total */
#define OFF_ROWNZ  2098176ul           /* u64[B][NW] -> pad 2KB */
#define OFF_BCNT   2100224ul           /* u32[B*NBUCK*16] (64B-padded counters) = 16KB */
#define OFF_ORDER  2116608ul           /* u32[B][PRE] */
#define OFF_SCORE  2164608ul           /* f32[B][PRE] */
#define OFF_BOXES  2212608ul           /* f32[B][PRE][6] */
#define OFF_MASKS  2500608ul           /* u64[B][PRE][MROW] = 4608000 */
#define OFF_KEPT   7108608ul           /* u32[B][PRE] -> end 7156608 */
#define MEMSET_OFF  2097152ul
#define MEMSET_BYTES 19456ul           /* info + rownz + bcnt only */

__device__ __forceinline__ u32 score_key(float f) {
  u32 u = __float_as_uint(f);
  return (u & 0x80000000u) ? ~u : (u | 0x80000000u);
}

/* ---------- 1. 12-bit LDS-privatized histogram, plain-store partials ---------- */
__global__ __launch_bounds__(256) void k_h12(const float* __restrict__ scores,
                                             u32* __restrict__ part) {
  __shared__ u32 lh[4096];
  int b = blockIdx.x >> 4, sub = blockIdx.x & (NSUB - 1);
  int tid = threadIdx.x;
  for (int i = tid; i < 4096; i += 256) lh[i] = 0;
  __syncthreads();
  const float4* src = (const float4*)(scores + (size_t)b * ANUM) + (size_t)sub * 2048;
#pragma unroll
  for (int it = 0; it < 8; ++it) {
    float4 v = src[it * 256 + tid];
    atomicAdd(&lh[score_key(v.x) >> 20], 1u);
    atomicAdd(&lh[score_key(v.y) >> 20], 1u);
    atomicAdd(&lh[score_key(v.z) >> 20], 1u);
    atomicAdd(&lh[score_key(v.w) >> 20], 1u);
  }
  __syncthreads();
  u32* P = part + (size_t)b * 4096 * NSUB;
  for (int i = tid; i < 4096; i += 256) P[i * NSUB + sub] = lh[i];
}

/* ---------- 2. find 12-bit bin crossing rank 3000 -> coarse threshold T ---------- */
__global__ void k_sel12(const u32* __restrict__ part, u32* __restrict__ info) {
  int b = blockIdx.x, tid = threadIdx.x;              /* 256 threads */
  __shared__ u32 strip[256];
  const u32* P = part + (size_t)b * 4096 * NSUB;
  u32 s = 0;
  for (int j = 0; j < 16; ++j) {                      /* thread t: bins 4095-16t .. */
    int bin = 4095 - (tid * 16 + j);
    u32 acc = 0;
#pragma unroll
    for (int sub = 0; sub < NSUB; ++sub) acc += P[bin * NSUB + sub];
    s += acc;
  }
  strip[tid] = s;
  __syncthreads();
  if (tid == 0) {
    u32 c = 0; int ts = 0; u32 cb = 0;
    for (int t = 0; t < 256; ++t) {
      if (c + strip[t] >= PRE) { ts = t; cb = c; break; }
      c += strip[t];
    }
    u32 cc = cb; int b12 = 0;
    for (int r = ts * 16; r < 4096; ++r) {
      int bin = 4095 - r;
      u32 acc = 0;
      for (int sub = 0; sub < NSUB; ++sub) acc += P[bin * NSUB + sub];
      if (cc + acc >= PRE) { b12 = bin; break; }
      cc += acc;
    }
    info[b] = (u32)b12;
    info[4 + b] = cc;                                  /* count strictly above bin */
    info[8 + b] = ((u32)b12) << 20;                    /* coarse threshold T32 */
  }
}

/* ---------- 3. compact candidates (key >= T) into per-bucket lists ---------- */
__global__ void k_compact(const float* __restrict__ scores, const u32* __restrict__ info,
                          u32* __restrict__ bcnt, u64* __restrict__ cand) {
  int t = blockIdx.x * blockDim.x + threadIdx.x;
  int b = t >> 17;
  int e = t & (ANUM - 1);
  int bucket = (blockIdx.x >> 3) & (NBUCK - 1);
  u32 key = score_key(scores[t]);
  if (key >= info[8 + b]) {
    u32 pos = atomicAdd(&bcnt[(u32)((b << 6) + bucket) * 16u], 1u);
    if (pos < BCAP) cand[(size_t)((b << 6) + bucket) * BCAP + pos] = ((u64)key << 32) | (u32)(~(u32)e);
  }
}

/* ---------- 4. gather buckets into dense zero-padded list ---------- */
__global__ __launch_bounds__(1024) void k_gather(const u64* __restrict__ cand,
                                                 const u32* __restrict__ bcnt,
                                                 u64* __restrict__ dense,
                                                 u32* __restrict__ info) {
  int b = blockIdx.x, tid = threadIdx.x;
  __shared__ u32 pref[NBUCK + 1];
  if (tid < NBUCK) {
    u32 c = bcnt[(u32)((b << 6) + tid) * 16u];
    if (c > BCAP) c = BCAP;
    u32 inc = c;
#pragma unroll
    for (int d = 1; d < 64; d <<= 1) {
      u32 v = __shfl_up(inc, d);
      if (tid >= d) inc += v;
    }
    pref[tid + 1] = inc;
    if (tid == 0) pref[0] = 0;
  }
  __syncthreads();
  u32 total = pref[NBUCK]; if (total > CAP) total = CAP;
  if (tid == 0) info[20 + b] = total;
  for (int i = tid; i < CAP; i += 1024) dense[(size_t)b * CAP + i] = 0ull;
  __syncthreads();
  for (int j = tid; j < NBUCK * BCAP; j += 1024) {
    int bk = j >> 8, sl = j & (BCAP - 1);
    u32 c = pref[bk + 1] - pref[bk];
    u32 pos = pref[bk] + (u32)sl;
    if ((u32)sl < c && pos < CAP) dense[(size_t)b * CAP + pos] = cand[(size_t)((b << 6) + bk) * BCAP + sl];
  }
}

/* ---------- 5. rank-by-counting ---------- */
__global__ __launch_bounds__(256) void k_rank(const u64* __restrict__ dense,
                                              const u32* __restrict__ info,
                                              u32* __restrict__ order,
                                              float* __restrict__ scoresel) {
  int b = blockIdx.y;
  int tid = threadIdx.x;
  int i = blockIdx.x * 256 + tid;
  __shared__ u64 tile[256];
  u64 mykey = dense[(size_t)b * CAP + i];
  int ntile = ((int)info[20 + b] + 255) >> 8;
  int rank = 0;
  for (int t = 0; t < ntile; ++t) {
    tile[tid] = dense[(size_t)b * CAP + t * 256 + tid];
    __syncthreads();
#pragma unroll 8
    for (int j = 0; j < 256; ++j) rank += (tile[j] > mykey) ? 1 : 0;
    __syncthreads();
  }
  if ((u32)mykey != 0u && rank < PRE) {
    u32 key = (u32)(mykey >> 32);
    u32 e = ~((u32)mykey);
    order[b * PRE + rank] = e;
    u32 u = (key & 0x80000000u) ? (key ^ 0x80000000u) : ~key;
    scoresel[b * PRE + rank] = __uint_as_float(u);
  }
}

/* ---------- 6. gather + box regression ---------- */
__global__ void k_regress(const float* __restrict__ anchors, const float* __restrict__ deltas,
                          const u32* __restrict__ order, float* __restrict__ boxes) {
  int t = blockIdx.x * blockDim.x + threadIdx.x;
  if (t >= BATCH * PRE) return;
  int b = t / PRE;
  u32 a = order[t];
  const float* an = anchors + (size_t)a * 6;
  const float* de = deltas + ((size_t)b * ANUM + a) * 6;
  float* out = boxes + (size_t)t * 6;
#pragma unroll
  for (int d = 0; d < 3; ++d) {
    float lo = an[d], hi = an[3 + d];
    float dims = __fsub_rn(hi, lo);
    float ctr = __fadd_rn(lo, __fmul_rn(0.5f, dims));
    ctr = __fadd_rn(ctr, __fmul_rn(de[d], dims));
    float nd = __fmul_rn(dims, expf(de[3 + d]));
    float h = __fmul_rn(0.5f, nd);
    out[d] = __fsub_rn(ctr, h);
    out[3 + d] = __fadd_rn(ctr, h);
  }
}

/* ---------- 7. suppression bitmask matrix (+ diag blocks + row-NZ bitmap) ---------- */
__global__ void k_mask(const float* __restrict__ boxes, u64* __restrict__ masks,
                       u64* __restrict__ diag, u64* __restrict__ rownz) {
  int jblk = blockIdx.x, iblk = blockIdx.y, b = blockIdx.z;
  int tid = threadIdx.x;                                /* 64 */
  __shared__ float cb[64][7];
  int j0 = jblk * 64;
  {
    int jj = j0 + tid; if (jj > PRE - 1) jj = PRE - 1;
    const float* src = boxes + ((size_t)b * PRE + jj) * 6;
#pragma unroll
    for (int d = 0; d < 6; ++d) cb[tid][d] = src[d];
    float dx = fmaxf(__fsub_rn(cb[tid][3], cb[tid][0]), 0.0f);
    float dy = fmaxf(__fsub_rn(cb[tid][4], cb[tid][1]), 0.0f);
    float dz = fmaxf(__fsub_rn(cb[tid][5], cb[tid][2]), 0.0f);
    cb[tid][6] = __fmul_rn(__fmul_rn(dx, dy), dz);
  }
  __syncthreads();
  int i = iblk * 64 + tid;
  if (i >= PRE) return;
  u64 bits = 0;
  if (j0 + 63 > i) {
    const float* rb = boxes + ((size_t)b * PRE + i) * 6;
    float l0 = rb[0], l1 = rb[1], l2 = rb[2], h0 = rb[3], h1 = rb[4], h2 = rb[5];
    float dx = fmaxf(__fsub_rn(h0, l0), 0.0f);
    float dy = fmaxf(__fsub_rn(h1, l1), 0.0f);
    float dz = fmaxf(__fsub_rn(h2, l2), 0.0f);
    float vi = __fmul_rn(__fmul_rn(dx, dy), dz);
    for (int c = 0; c < 64; ++c) {
      int j = j0 + c;
      if (j > i && j < PRE) {
        float ix = fmaxf(__fsub_rn(fminf(h0, cb[c][3]), fmaxf(l0, cb[c][0])), 0.0f);
        float iy = fmaxf(__fsub_rn(fminf(h1, cb[c][4]), fmaxf(l1, cb[c][1])), 0.0f);
        float iz = fmaxf(__fsub_rn(fminf(h2, cb[c][5]), fmaxf(l2, cb[c][2])), 0.0f);
        float iv = __fmul_rn(__fmul_rn(ix, iy), iz);
        float un = fmaxf(__fsub_rn(__fadd_rn(vi, cb[c][6]), iv), 1e-8f);
        float iou = __fdiv_rn(iv, un);
        if (iou > 0.7f) bits |= (1ull << c);
      }
    }
  }
  masks[((size_t)b * PRE + i) * MROW + jblk] = bits;
  if (iblk == jblk) diag[((size_t)b * NW + jblk) * 64 + tid] = bits;
  u64 bal = __ballot(bits != 0ull);
  if (tid == 0 && bal) atomicOr(&rownz[b * NW + iblk], bal);
}

/* ---------- 8. sparse single-wave NMS scan ---------- */
__global__ __launch_bounds__(64) void k_scan(const u64* __restrict__ masks,
                                             const u64* __restrict__ diag,
                                             const u64* __restrict__ rownz,
                                             u32* __restrict__ kept,
                                             u32* __restrict__ info) {
  int b = blockIdx.x;
  int lane = threadIdx.x;                               /* 64 */
  const u64* Mb = masks + (size_t)b * PRE * MROW;
  const u64* Db = diag + (size_t)b * NW * 64;
  const u64* Nb = rownz + b * NW;
  int wl = lane < NW ? lane : NW - 1;
  u64 rem = 0;
  int cnt = 0;

  u64 dcur = Db[lane];

  for (int c = 0; c < NW; ++c) {
    int base = c * 64;
    int nrow = (base + 64 <= PRE) ? 64 : (PRE - base);

    u64 dn = (c + 1 < NW) ? Db[(size_t)(c + 1) * 64 + lane] : 0ull;
    u64 nzc = Nb[c];

    u32 rlo = __shfl((u32)rem, c);
    u32 rhi = __shfl((u32)(rem >> 32), c);
    u64 pending = ~(((u64)rhi << 32) | (u64)rlo);
    if (nrow < 64) pending &= ((1ull << nrow) - 1ull);

    u64 Z = __ballot(dcur != 0ull);
    u64 chain = pending & Z;
    while (chain) {
      int k = __builtin_ctzll(chain);
      u32 rl = (u32)__builtin_amdgcn_readlane((int)(u32)dcur, k);
      u32 rh = (u32)__builtin_amdgcn_readlane((int)(u32)(dcur >> 32), k);
      u64 rw = ((u64)rh << 32) | (u64)rl;
      pending &= ~rw;
      chain &= pending;
      chain &= ~(1ull << k);
    }
    u64 keep = pending;

    u64 ltmask = (lane == 0) ? 0ull : (~0ull >> (64 - lane));
    int pos = __popcll(keep & ltmask);
    if ((keep >> lane) & 1ull) kept[b * PRE + cnt + pos] = (u32)(base + lane);
    cnt += (int)__popcll(keep);

    if (cnt >= MAXOUT) break;

    u64 nz = keep & nzc;
    while (nz) {
      int rks[8]; int m = 0; int rr = base;
#pragma unroll
      for (int s = 0; s < 8; ++s) {
        if (nz) { rr = base + __builtin_ctzll(nz); nz &= nz - 1; ++m; }
        rks[s] = rr;
      }
      u64 v[8];
#pragma unroll
      for (int s = 0; s < 8; ++s) v[s] = Mb[(size_t)rks[s] * MROW + wl];
      u64 acc = 0;
#pragma unroll
      for (int s = 0; s < 8; ++s) acc |= (s < m) ? v[s] : 0ull;
      rem |= acc;
    }

    dcur = dn;
  }
  if (lane == 0) info[16 + b] = (u32)cnt;
}

/* ---------- 9. output assembly ---------- */
__global__ void k_out(const float* __restrict__ boxes, const float* __restrict__ scoresel,
                      const u32* __restrict__ kept, const u32* __restrict__ info,
                      float* __restrict__ out) {
  int b = blockIdx.x, tid = threadIdx.x;                /* 256 */
  int cnt = (int)info[16 + b]; if (cnt > MAXOUT) cnt = MAXOUT;
  for (int k = tid; k < MAXOUT; k += 256) {
    float pr[6] = {0.f, 0.f, 0.f, 0.f, 0.f, 0.f};
    float s = 0.f, v = 0.f;
    if (k < cnt) {
      u32 i = kept[b * PRE + k];
      const float* bx = boxes + ((size_t)b * PRE + i) * 6;
#pragma unroll
      for (int d = 0; d < 6; ++d) pr[d] = bx[d];
      s = scoresel[b * PRE + i];
      v = 1.f;
    }
    float* pp = out + ((size_t)(b * MAXOUT + k)) * 6;
#pragma unroll
    for (int d = 0; d < 6; ++d) pp[d] = pr[d];
    out[BATCH * MAXOUT * 6 + b * MAXOUT + k] = s;
    out[BATCH * MAXOUT * 7 + b * MAXOUT + k] = (float)b;
    out[BATCH * MAXOUT * 8 + b * MAXOUT + k] = v;
  }
}

extern "C" void kernel_launch(void* const* d_in, const int* in_sizes, int n_in,
                              void* d_out, int out_size, void* d_ws, size_t ws_size,
                              hipStream_t stream) {
  const float* anchors = (const float*)d_in[0];
  const float* scores  = (const float*)d_in[1];
  const float* deltas  = (const float*)d_in[2];
  float* out = (float*)d_out;

  char* w = (char*)d_ws;
  u32* part    = (u32*)(w + OFF_PART);
  u64* cand    = (u64*)(w + OFF_CAND);
  u64* diag    = (u64*)(w + OFF_DIAG);
  u64* dense   = (u64*)(w + OFF_DENSE);
  u32* info    = (u32*)(w + OFF_INFO);
  u64* rownz   = (u64*)(w + OFF_ROWNZ);
  u32* bcnt    = (u32*)(w + OFF_BCNT);
  u32* order   = (u32*)(w + OFF_ORDER);
  float* scoresel = (float*)(w + OFF_SCORE);
  float* boxes = (float*)(w + OFF_BOXES);
  u64* masks   = (u64*)(w + OFF_MASKS);
  u32* kept    = (u32*)(w + OFF_KEPT);

  hipMemsetAsync(w + MEMSET_OFF, 0, MEMSET_BYTES, stream);

  int nElem = BATCH * ANUM;
  k_h12<<<BATCH * NSUB, 256, 0, stream>>>(scores, part);
  k_sel12<<<BATCH, 256, 0, stream>>>(part, info);
  k_compact<<<nElem / 256, 256, 0, stream>>>(scores, info, bcnt, cand);
  k_gather<<<BATCH, 1024, 0, stream>>>(cand, bcnt, dense, info);
  k_rank<<<dim3(CAP / 256, BATCH), 256, 0, stream>>>(dense, info, order, scoresel);
  k_regress<<<(BATCH * PRE + 255) / 256, 256, 0, stream>>>(anchors, deltas, order, boxes);
  k_mask<<<dim3(NW, NW, BATCH), 64, 0, stream>>>(boxes, masks, diag, rownz);
  k_scan<<<BATCH, 64, 0, stream>>>(masks, diag, rownz, kept, info);
  k_out<<<BATCH, 256, 0, stream>>>(boxes, scoresel, kept, info, out);
}